// Round 6
// baseline (258.251 us; speedup 1.0000x reference)
//
#include <hip/hip_runtime.h>
#include <hip/hip_bf16.h>

// EditOuterAttention — round 6.
// out = softmax((x Wq + bq)(y Wk + bk)^T / 8 + mask) (y Wv + bv) Wo + bo
// BS=2, LX=LY=2048, D=1024, H=16, DK=64.
//
// Round-6 delta (GEMM epilogues only; attn untouched):
//  - qkv_gemm z<=1: acc -> LDS Ct (pad 136) -> 8 coalesced b128 stores/thread
//    (was 64 scattered global_store_short/thread; K=1024 => epilogue was a big slice)
//  - out_gemm: acc -> f32 LDS Ct (pad 68) -> 8 coalesced float4 stores/thread

typedef __bf16 bf16;
typedef __bf16 bf16x4 __attribute__((ext_vector_type(4)));
typedef __bf16 bf16x8 __attribute__((ext_vector_type(8)));
typedef float floatx4 __attribute__((ext_vector_type(4)));

#define MFMA16(a, b, c) __builtin_amdgcn_mfma_f32_16x16x32_bf16(a, b, c, 0, 0, 0)

constexpr int BS = 2, LX = 2048, LY = 2048, D = 1024, H = 16, DK = 64;
constexpr int HD = H * DK;  // 1024
constexpr float LOG2E = 1.4426950408889634f;

// ---- async global->LDS, 16B per lane; HW writes LDS at wave-uniform base + lane*16.
// Staging with per-lane global addr (row=lane>>3, chunk=(lane&7)^row) yields XOR-swizzled LDS;
// readers unswizzle with slot = chunk ^ (row&7).
__device__ __forceinline__ void cp16(const bf16* g, bf16* l) {
  __builtin_amdgcn_global_load_lds(
      (const __attribute__((address_space(1))) unsigned int*)g,
      (__attribute__((address_space(3))) unsigned int*)l, 16, 0, 0);
}

// ---------------- fused prep: weight transpose x4 | x,y bf16 convert | mask scan ----------------
__global__ __launch_bounds__(256) void prep(const float* __restrict__ W0, bf16* __restrict__ T0,
                                            const float* __restrict__ W1, bf16* __restrict__ T1,
                                            const float* __restrict__ W2, bf16* __restrict__ T2,
                                            const float* __restrict__ W3, bf16* __restrict__ T3,
                                            const float* __restrict__ x, bf16* __restrict__ xb,
                                            const float* __restrict__ y, bf16* __restrict__ yb,
                                            const float* __restrict__ mask, int* __restrict__ flags) {
  const int id = blockIdx.x;
  const int t = threadIdx.x;
  if (id < 1024) {
    __shared__ bf16 tile[64][72];
    const float* W;
    bf16* T;
    switch (id >> 8) {
      case 0: W = W0; T = T0; break;
      case 1: W = W1; T = T1; break;
      case 2: W = W2; T = T2; break;
      default: W = W3; T = T3; break;
    }
    const int kt = id & 15, nt = (id >> 4) & 15;
    const int r = t >> 2, c4 = (t & 3) * 16;
    const float* src = W + (size_t)(kt * 64 + r) * 1024 + nt * 64 + c4;
#pragma unroll
    for (int i = 0; i < 16; i++) tile[r][c4 + i] = (bf16)src[i];
    __syncthreads();
    bf16 vals[16];
#pragma unroll
    for (int i = 0; i < 16; i++) vals[i] = tile[c4 + i][r];
    bf16* dst = T + (size_t)(nt * 64 + r) * 1024 + kt * 64 + c4;
#pragma unroll
    for (int i = 0; i < 16; i++) dst[i] = vals[i];
  } else if (id < 5120) {
    const int id2 = id - 1024;
    const float* src = (id2 >= 2048) ? y : x;
    bf16* dst = (id2 >= 2048) ? yb : xb;
    const size_t i = ((size_t)(id2 & 2047) * 256 + t) * 8;
    float4 a = *(const float4*)(src + i);
    float4 c = *(const float4*)(src + i + 4);
    bf16 tmp[8] = {(bf16)a.x, (bf16)a.y, (bf16)a.z, (bf16)a.w,
                   (bf16)c.x, (bf16)c.y, (bf16)c.z, (bf16)c.w};
    *(bf16x8*)(dst + i) = *(const bf16x8*)tmp;
  } else {
    const int id3 = id - 5120;
    const int region = id3 >> 5, sub = id3 & 31;
    const float4* p = (const float4*)mask + (size_t)region * 65536 + sub * 2048;
    bool nz = false;
#pragma unroll
    for (int it = 0; it < 8; it++) {
      float4 v = p[it * 256 + t];
      nz |= (v.x != 0.f) | (v.y != 0.f) | (v.z != 0.f) | (v.w != 0.f);
    }
    if (nz) atomicOr(&flags[region], 1);
  }
}

// ---------------- fused QKV projection GEMM (128x128, BK=64) ----------------
__global__ __launch_bounds__(256) void qkv_gemm(const bf16* __restrict__ xb, const bf16* __restrict__ yb,
                                                const bf16* __restrict__ Wtq, const bf16* __restrict__ Wtk,
                                                const bf16* __restrict__ Wtv,
                                                const float* __restrict__ bq, const float* __restrict__ bk,
                                                const float* __restrict__ bv,
                                                bf16* __restrict__ Qb, bf16* __restrict__ Kb,
                                                bf16* __restrict__ Vt) {
  constexpr int K = 1024, N = 1024;
  __shared__ __align__(16) bf16 smem[128 * 136];
  bf16* As = smem;
  bf16* Bs = smem + 128 * 64;
  bf16* Ct = smem;

  const int z = blockIdx.z;
  const bf16* A = (z == 0) ? xb : yb;
  const bf16* Bt = (z == 0) ? Wtq : (z == 1) ? Wtk : Wtv;
  const float* bias = (z == 0) ? bq : (z == 1) ? bk : bv;

  const int t = threadIdx.x;
  const int w = t >> 6, lane = t & 63, quad = lane >> 4, l15 = lane & 15;
  const int wr = (w & 1) * 64, wc = (w >> 1) * 64;
  const int mbase = blockIdx.y * 128, nbase = blockIdx.x * 128;
  const int srow = lane >> 3, schunk = (lane & 7) ^ srow;
  const int sx = quad ^ (l15 & 7);

  floatx4 acc[4][4] = {};

  for (int k0 = 0; k0 < K; k0 += 64) {
    __syncthreads();
#pragma unroll
    for (int j = 0; j < 4; j++) {
      const int r0 = w * 32 + j * 8;
      cp16(A + (size_t)(mbase + r0 + srow) * K + k0 + schunk * 8, As + r0 * 64);
      cp16(Bt + (size_t)(nbase + r0 + srow) * K + k0 + schunk * 8, Bs + r0 * 64);
    }
    __syncthreads();
    bf16x8 af[4][2], bfr[4][2];
#pragma unroll
    for (int i = 0; i < 4; i++) {
      const int ra = wr + i * 16 + l15;
      af[i][0] = *(const bf16x8*)&As[ra * 64 + sx * 8];
      af[i][1] = *(const bf16x8*)&As[ra * 64 + (sx ^ 4) * 8];
      const int rb = wc + i * 16 + l15;
      bfr[i][0] = *(const bf16x8*)&Bs[rb * 64 + sx * 8];
      bfr[i][1] = *(const bf16x8*)&Bs[rb * 64 + (sx ^ 4) * 8];
    }
#pragma unroll
    for (int i = 0; i < 4; i++)
#pragma unroll
      for (int jn = 0; jn < 4; jn++) {
        acc[i][jn] = MFMA16(af[i][0], bfr[jn][0], acc[i][jn]);
        acc[i][jn] = MFMA16(af[i][1], bfr[jn][1], acc[i][jn]);
      }
  }

  __syncthreads();  // all waves done reading As/Bs; smem reused as Ct
  if (z <= 1) {
    bf16* outp = (z == 0) ? Qb : Kb;
    const float sc = (z == 0) ? 0.125f * LOG2E : 1.0f;
#pragma unroll
    for (int jn = 0; jn < 4; jn++) {
      const int nl = wc + jn * 16 + l15;
      const float bv2 = bias[nbase + nl];
#pragma unroll
      for (int i = 0; i < 4; i++)
#pragma unroll
        for (int r = 0; r < 4; r++) {
          const int ml = wr + i * 16 + quad * 4 + r;
          Ct[ml * 136 + nl] = (bf16)((acc[i][jn][r] + bv2) * sc);
        }
    }
    __syncthreads();
    // coalesced: thread t -> row t>>1, n-half (t&1)*64 : 8 x b128
    const int row = t >> 1, c0 = (t & 1) * 64;
    bf16* dst = outp + (size_t)(mbase + row) * N + nbase + c0;
    const bf16* srcr = &Ct[row * 136 + c0];
#pragma unroll
    for (int u = 0; u < 8; u++) *(bf16x8*)(dst + u * 8) = *(const bf16x8*)(srcr + u * 8);
  } else {
    // V: transpose to (b,h,dk,y) via LDS (Ct indexed [n][m])
#pragma unroll
    for (int jn = 0; jn < 4; jn++) {
      const int nl = wc + jn * 16 + l15;
      const float bv2 = bias[nbase + nl];
#pragma unroll
      for (int i = 0; i < 4; i++)
#pragma unroll
        for (int r = 0; r < 4; r++) {
          const int ml = wr + i * 16 + quad * 4 + r;
          Ct[nl * 136 + ml] = (bf16)(acc[i][jn][r] + bv2);
        }
    }
    __syncthreads();
    const int n = t >> 1, mh = (t & 1) * 64;
    const int gn = nbase + n;
    const int hh = gn >> 6, dk = gn & 63;
    const int bb = mbase >> 11, y0 = (mbase & 2047) + mh;
    bf16* dst = Vt + ((size_t)(bb * H + hh) * DK + dk) * LY + y0;
    const bf16* srcr = &Ct[n * 136 + mh];
#pragma unroll
    for (int u = 0; u < 8; u++) *(bf16x8*)(dst + u * 8) = *(const bf16x8*)(srcr + u * 8);
  }
}

// ---------------- out GEMM: d_out = Hb @ Wo^T + bo (f32), 128M x 64N tiles ----------------
__global__ __launch_bounds__(256) void out_gemm(const bf16* __restrict__ A, const bf16* __restrict__ Bt,
                                                const float* __restrict__ bias, float* __restrict__ outp) {
  constexpr int K = 1024, N = 1024;
  __shared__ __align__(16) char smem[128 * 68 * 4];  // 34.8 KB: As(16K)+Bs(8K) aliased with f32 Ct
  bf16* As = (bf16*)smem;             // 128 x 64
  bf16* Bs = (bf16*)smem + 128 * 64;  // 64 x 64
  float* Cf = (float*)smem;           // 128 x 68
  const int t = threadIdx.x;
  const int w = t >> 6, lane = t & 63, quad = lane >> 4, l15 = lane & 15;
  const int mbase = blockIdx.y * 128, nbase = blockIdx.x * 64;
  const int srow = lane >> 3, schunk = (lane & 7) ^ srow;
  const int sx = quad ^ (l15 & 7);

  floatx4 acc[2][4] = {};
  for (int k0 = 0; k0 < K; k0 += 64) {
    __syncthreads();
#pragma unroll
    for (int j = 0; j < 4; j++) {
      const int r0 = w * 32 + j * 8;
      cp16(A + (size_t)(mbase + r0 + srow) * K + k0 + schunk * 8, As + r0 * 64);
    }
#pragma unroll
    for (int j = 0; j < 2; j++) {
      const int r0 = w * 16 + j * 8;
      cp16(Bt + (size_t)(nbase + r0 + srow) * K + k0 + schunk * 8, Bs + r0 * 64);
    }
    __syncthreads();
    bf16x8 af[2][2], bfr[4][2];
#pragma unroll
    for (int i = 0; i < 2; i++) {
      const int ra = w * 32 + i * 16 + l15;
      af[i][0] = *(const bf16x8*)&As[ra * 64 + sx * 8];
      af[i][1] = *(const bf16x8*)&As[ra * 64 + (sx ^ 4) * 8];
    }
#pragma unroll
    for (int jn = 0; jn < 4; jn++) {
      const int rb = jn * 16 + l15;
      bfr[jn][0] = *(const bf16x8*)&Bs[rb * 64 + sx * 8];
      bfr[jn][1] = *(const bf16x8*)&Bs[rb * 64 + (sx ^ 4) * 8];
    }
#pragma unroll
    for (int i = 0; i < 2; i++)
#pragma unroll
      for (int jn = 0; jn < 4; jn++) {
        acc[i][jn] = MFMA16(af[i][0], bfr[jn][0], acc[i][jn]);
        acc[i][jn] = MFMA16(af[i][1], bfr[jn][1], acc[i][jn]);
      }
  }
  __syncthreads();  // done reading As/Bs; reuse as Cf
#pragma unroll
  for (int jn = 0; jn < 4; jn++) {
    const int nl = jn * 16 + l15;
    const float bv2 = bias[nbase + nl];
#pragma unroll
    for (int i = 0; i < 2; i++)
#pragma unroll
      for (int r = 0; r < 4; r++) {
        const int ml = w * 32 + i * 16 + quad * 4 + r;
        Cf[ml * 68 + nl] = acc[i][jn][r] + bv2;
      }
  }
  __syncthreads();
  // coalesced: thread t -> row t>>1, n-half (t&1)*32 : 8 x float4
  const int row = t >> 1, c0 = (t & 1) * 32;
  float* dst = outp + (size_t)(mbase + row) * N + nbase + c0;
  const float* srcr = &Cf[row * 68 + c0];
#pragma unroll
  for (int u = 0; u < 8; u++) *(float4*)(dst + u * 4) = *(const float4*)(srcr + u * 4);
}

// ---------------- flash attention (unchanged from round 5) ----------------
__global__ __launch_bounds__(256, 2) void attn5(const bf16* __restrict__ Q, const bf16* __restrict__ Kb,
                                                const bf16* __restrict__ Vt, const float* __restrict__ mask,
                                                const int* __restrict__ flags, bf16* __restrict__ Hout) {
  __shared__ __align__(16) bf16 Ks[2][64 * 64];
  __shared__ __align__(16) bf16 Vs[2][64 * 64];
  __shared__ __align__(16) bf16 Plds[4][32 * 72];
  const int t = threadIdx.x;
  const int w = t >> 6, lane = t & 63, quad = lane >> 4, l15 = lane & 15;
  const int xt = blockIdx.x, h = blockIdx.y, b = blockIdx.z;
  const int qbase = xt * 128 + w * 32;
  const int srow = lane >> 3, schunk = (lane & 7) ^ srow;
  const int sx = quad ^ (l15 & 7);

  bf16x8 qf[2][2];
#pragma unroll
  for (int rt = 0; rt < 2; rt++) {
    const bf16* qrow = Q + (size_t)(b * LX + qbase + rt * 16 + l15) * HD + h * DK;
    qf[rt][0] = *(const bf16x8*)(qrow + quad * 8);
    qf[rt][1] = *(const bf16x8*)(qrow + 32 + quad * 8);
  }
  const int mflag = flags[b * 16 + xt];

  bf16 onearr[8];
#pragma unroll
  for (int i = 0; i < 8; i++) onearr[i] = (bf16)((l15 == 0) ? 1.0f : 0.0f);
  const bf16x8 onesf = *(const bf16x8*)onearr;

  floatx4 o[2][4] = {};
  floatx4 ol[2] = {};

  const bf16* Kbase = Kb + (size_t)b * LY * HD + h * DK;
  const bf16* Vbase = Vt + (size_t)(b * H + h) * DK * LY;
  const float* mbase2 = mask + (size_t)(b * LX + qbase + l15) * LY;

#define STAGE(yt, bufi)                                                               \
  {                                                                                   \
    _Pragma("unroll") for (int j = 0; j < 2; j++) {                                   \
      const int r0 = w * 16 + j * 8;                                                  \
      cp16(Kbase + (size_t)((yt) + r0 + srow) * HD + schunk * 8, &Ks[bufi][r0 * 64]); \
      cp16(Vbase + (size_t)(r0 + srow) * LY + (yt) + schunk * 8, &Vs[bufi][r0 * 64]); \
    }                                                                                 \
  }

#define TILE(yt, BUF)                                                                  \
  {                                                                                    \
    const bf16* KsB = Ks[BUF];                                                         \
    const bf16* VsB = Vs[BUF];                                                         \
    bf16x8 kf[4][2];                                                                   \
    _Pragma("unroll") for (int nt = 0; nt < 4; nt++) {                                 \
      const int ry = nt * 16 + l15;                                                    \
      kf[nt][0] = *(const bf16x8*)&KsB[ry * 64 + sx * 8];                              \
      kf[nt][1] = *(const bf16x8*)&KsB[ry * 64 + (sx ^ 4) * 8];                        \
    }                                                                                  \
    floatx4 s[2][4] = {};                                                              \
    _Pragma("unroll") for (int nt = 0; nt < 4; nt++)                                   \
        _Pragma("unroll") for (int rt = 0; rt < 2; rt++) {                             \
      s[rt][nt] = MFMA16(kf[nt][0], qf[rt][0], s[rt][nt]);                             \
      s[rt][nt] = MFMA16(kf[nt][1], qf[rt][1], s[rt][nt]);                             \
    }                                                                                  \
    if (mflag) {                                                                       \
      _Pragma("unroll") for (int rt = 0; rt < 2; rt++)                                 \
          _Pragma("unroll") for (int nt = 0; nt < 4; nt++) {                           \
        const float* mp = mbase2 + (size_t)rt * 16 * LY + (yt) + nt * 16 + quad * 4;   \
        float4 mv = *(const float4*)mp;                                                \
        s[rt][nt][0] = fminf(s[rt][nt][0] + LOG2E * mv.x, 30.f);                       \
        s[rt][nt][1] = fminf(s[rt][nt][1] + LOG2E * mv.y, 30.f);                       \
        s[rt][nt][2] = fminf(s[rt][nt][2] + LOG2E * mv.z, 30.f);                       \
        s[rt][nt][3] = fminf(s[rt][nt][3] + LOG2E * mv.w, 30.f);                       \
      }                                                                                \
    }                                                                                  \
    _Pragma("unroll") for (int rt = 0; rt < 2; rt++)                                   \
        _Pragma("unroll") for (int nt = 0; nt < 4; nt++) {                             \
      bf16x4 pk;                                                                       \
      _Pragma("unroll") for (int r = 0; r < 4; r++) pk[r] = (bf16)exp2f(s[rt][nt][r]); \
      *(bf16x4*)&Plds[w][(rt * 16 + l15) * 72 + nt * 16 + quad * 4] = pk;              \
    }                                                                                  \
    bf16x8 pf[2][2];                                                                   \
    _Pragma("unroll") for (int rt = 0; rt < 2; rt++) {                                 \
      const bf16* prow = &Plds[w][(rt * 16 + l15) * 72];                               \
      pf[rt][0] = *(const bf16x8*)(prow + quad * 8);                                   \
      pf[rt][1] = *(const bf16x8*)(prow + 32 + quad * 8);                              \
    }                                                                                  \
    _Pragma("unroll") for (int u = 0; u < 4; u++) {                                    \
      const int rd = u * 16 + l15;                                                     \
      bf16x8 v0 = *(const bf16x8*)&VsB[rd * 64 + sx * 8];                              \
      bf16x8 v1 = *(const bf16x8*)&VsB[rd * 64 + (sx ^ 4) * 8];                        \
      _Pragma("unroll") for (int rt = 0; rt < 2; rt++) {                               \
        o[rt][u] = MFMA16(pf[rt][0], v0, o[rt][u]);                                    \
        o[rt][u] = MFMA16(pf[rt][1], v1, o[rt][u]);                                    \
      }                                                                                \
    }                                                                                  \
    _Pragma("unroll") for (int rt = 0; rt < 2; rt++) {                                 \
      ol[rt] = MFMA16(pf[rt][0], onesf, ol[rt]);                                       \
      ol[rt] = MFMA16(pf[rt][1], onesf, ol[rt]);                                       \
    }                                                                                  \
  }

  STAGE(0, 0);
  for (int yt = 0; yt < LY; yt += 128) {
    __syncthreads();
    STAGE(yt + 64, 1);
    TILE(yt, 0);
    __syncthreads();
    if (yt + 128 < LY) STAGE(yt + 128, 0);
    TILE(yt + 64, 1);
  }

#pragma unroll
  for (int rt = 0; rt < 2; rt++)
#pragma unroll
    for (int r = 0; r < 4; r++) {
      const float lsum = __shfl(ol[rt][r], lane & 48, 64);
      const float rl = 1.0f / lsum;
      const int m = b * LX + qbase + rt * 16 + quad * 4 + r;
#pragma unroll
      for (int u = 0; u < 4; u++)
        Hout[(size_t)m * HD + h * DK + u * 16 + l15] = (bf16)(o[rt][u][r] * rl);
    }
#undef STAGE
#undef TILE
}

// ---------------- launch ----------------
extern "C" void kernel_launch(void* const* d_in, const int* in_sizes, int n_in,
                              void* d_out, int out_size, void* d_ws, size_t ws_size,
                              hipStream_t stream) {
  const float* x = (const float*)d_in[0];
  const float* y = (const float*)d_in[1];
  const float* mask = (const float*)d_in[2];
  const float* Wq = (const float*)d_in[3];
  const float* bq = (const float*)d_in[4];
  const float* Wk = (const float*)d_in[5];
  const float* bk = (const float*)d_in[6];
  const float* Wv = (const float*)d_in[7];
  const float* bv = (const float*)d_in[8];
  const float* Wo = (const float*)d_in[9];
  const float* bo = (const float*)d_in[10];

  char* ws = (char*)d_ws;
  size_t off = 0;
  bf16* Qb = (bf16*)(ws + off); off += (size_t)BS * LX * HD * 2;
  bf16* Kb = (bf16*)(ws + off); off += (size_t)BS * LY * HD * 2;
  bf16* Vt = (bf16*)(ws + off); off += (size_t)BS * LY * HD * 2;  // (b,h,dk,y)
  bf16* Hb = (bf16*)(ws + off); off += (size_t)BS * LX * HD * 2;
  bf16* xbf = (bf16*)(ws + off); off += (size_t)BS * LX * D * 2;
  bf16* ybf = (bf16*)(ws + off); off += (size_t)BS * LY * D * 2;
  bf16* Wtq = (bf16*)(ws + off); off += (size_t)D * HD * 2;
  bf16* Wtk = (bf16*)(ws + off); off += (size_t)D * HD * 2;
  bf16* Wtv = (bf16*)(ws + off); off += (size_t)D * HD * 2;
  bf16* Wto = (bf16*)(ws + off); off += (size_t)HD * D * 2;
  int* flags = (int*)(ws + off); off += 32 * sizeof(int);

  dim3 blk(256);
  hipMemsetAsync(flags, 0, 32 * sizeof(int), stream);
  prep<<<dim3(6144), blk, 0, stream>>>(Wq, Wtq, Wk, Wtk, Wv, Wtv, Wo, Wto, x, xbf, y, ybf, mask, flags);
  qkv_gemm<<<dim3(8, 32, 3), blk, 0, stream>>>(xbf, ybf, Wtq, Wtk, Wtv, bq, bk, bv, Qb, Kb, Vt);
  attn5<<<dim3(16, 16, 2), blk, 0, stream>>>(Qb, Kb, Vt, mask, flags, Hb);
  out_gemm<<<dim3(16, 32), blk, 0, stream>>>(Hb, Wto, bo, (float*)d_out);
}